// Round 4
// baseline (960.831 us; speedup 1.0000x reference)
//
#include <hip/hip_runtime.h>

// RecurrentCrossLinearAttention: N=16, S=4096, H=16, D=64, M=64, fp32.
// Round 4: wave-autonomous design. Grid 256 (1 block/CU), 1024 threads =
// 16 waves (4/SIMD = CU max at <=128 VGPR). Each wave independently streams
// 256 s-rows through its private 4 KB LDS slice -- NO __syncthreads in the
// hot loop (per-wave in-order DS pipe + wave_barrier for compiler ordering).
// This removes the barrier convoy (round 1/3: 7050cyc wall vs 2800cyc VALU
// per chunk) and gives 16 independent load streams per CU for MLP.
// End: 4-buffer parallel LDS merge + epilogue. No d_ws, single kernel.

#define S_LEN  4096
#define NHEAD  16
#define DDIM   64
#define MDIM   64
#define NWAVE  16
#define RPW    (S_LEN / NWAVE)    // 256 rows per wave
#define CROWS  8                  // rows per chunk
#define NCH    (RPW / CROWS)      // 32 chunks

#define OUT_SOFF  (16 * 16 * 64)               // N*H*M
#define OUT_ZOFF  (OUT_SOFF + 16 * 16 * 64 * 64)

__device__ __forceinline__ float elup1(float x) {
    // elu(x) + 1 = x+1 (x>0) else exp(x)
    return x > 0.0f ? x + 1.0f : __expf(x);
}

// launch_bounds 2nd arg = min BLOCKS/CU (CUDA semantics on this hipcc;
// verified r2: (512,4)->VGPR 64+spills, r3: (512,2)->124). (1024,1) -> cap 128.
__global__ __launch_bounds__(1024, 1)
void rcla_fused(const float* __restrict__ query,
                const float* __restrict__ keys,
                const float* __restrict__ values,
                const float* __restrict__ kmask,
                float* __restrict__ out)
{
    __shared__ float Ks[NWAVE][CROWS][DDIM];   // 32 KB, per-wave slices
    __shared__ float Vs[NWAVE][CROWS][MDIM];   // 32 KB
    __shared__ float buf4[4][MDIM * DDIM];     // 64 KB merge buffers
    __shared__ float zb4[4][DDIM];
    __shared__ float qb[DDIM];

    const int t    = threadIdx.x;              // 0..1023
    const int wave = t >> 6;                   // 0..15
    const int lane = t & 63;
    const int pair = blockIdx.x;               // n*16 + h
    const int nIdx = pair >> 4;
    const int hIdx = pair & 15;

    const int srow = lane >> 3;                // 0..7: staged row within chunk
    const int scol = (lane & 7) * 8;           // 8 floats of that row
    const int m0   = (lane >> 3) * 8;          // output tile row block
    const int d0   = (lane & 7) * 8;           // output tile col block

    const size_t rowStride = (size_t)NHEAD * DDIM;        // 1024 floats
    const int    sBase = wave * RPW + srow;
    const float* kp = keys   + ((size_t)nIdx * S_LEN + sBase) * rowStride
                             + (size_t)hIdx * DDIM + scol;
    const float* vp = values + ((size_t)nIdx * S_LEN + sBase) * rowStride
                             + (size_t)hIdx * DDIM + scol;
    const float* mp = kmask + (size_t)nIdx * S_LEN + sBase;
    const size_t step = (size_t)CROWS * rowStride;

    float acc[8][8];
    float zz[8];
#pragma unroll
    for (int i = 0; i < 8; ++i) {
        zz[i] = 0.0f;
#pragma unroll
        for (int j = 0; j < 8; ++j) acc[i][j] = 0.0f;
    }

    // prologue: chunk-0 loads (64 B/lane: 2x float4 K + 2x float4 V + mask)
    float4 ka = *(const float4*)kp;
    float4 kb = *(const float4*)(kp + 4);
    float4 va = *(const float4*)vp;
    float4 vb = *(const float4*)(vp + 4);
    float  mk = *mp;

    for (int c = 0; c < NCH; ++c) {
        // transform K in registers (waits on in-flight loads)
        float4 k0, k1;
        k0.x = elup1(ka.x) * mk;  k0.y = elup1(ka.y) * mk;
        k0.z = elup1(ka.z) * mk;  k0.w = elup1(ka.w) * mk;
        k1.x = elup1(kb.x) * mk;  k1.y = elup1(kb.y) * mk;
        k1.z = elup1(kb.z) * mk;  k1.w = elup1(kb.w) * mk;
        const float4 v0 = va, v1 = vb;

        __builtin_amdgcn_wave_barrier();       // order vs prior chunk's reads
        *(float4*)&Ks[wave][srow][scol]     = k0;
        *(float4*)&Ks[wave][srow][scol + 4] = k1;
        *(float4*)&Vs[wave][srow][scol]     = v0;
        *(float4*)&Vs[wave][srow][scol + 4] = v1;
        __builtin_amdgcn_wave_barrier();       // writes before reads

        if (c + 1 < NCH) {                     // issue next-chunk loads early
            kp += step; vp += step; mp += CROWS;
            ka = *(const float4*)kp;
            kb = *(const float4*)(kp + 4);
            va = *(const float4*)vp;
            vb = *(const float4*)(vp + 4);
            mk = *mp;
        }

        // compute this wave's 8 rows (wave-synchronous: in-order DS pipe
        // guarantees the ds_writes above complete before these ds_reads)
#pragma unroll
        for (int r = 0; r < CROWS; ++r) {
            const float4 kk0 = *(const float4*)&Ks[wave][r][d0];
            const float4 kk1 = *(const float4*)&Ks[wave][r][d0 + 4];
            const float4 vv0 = *(const float4*)&Vs[wave][r][m0];
            const float4 vv1 = *(const float4*)&Vs[wave][r][m0 + 4];
            const float kv[8] = {kk0.x, kk0.y, kk0.z, kk0.w, kk1.x, kk1.y, kk1.z, kk1.w};
            const float vm[8] = {vv0.x, vv0.y, vv0.z, vv0.w, vv1.x, vv1.y, vv1.z, vv1.w};
#pragma unroll
            for (int mi = 0; mi < 8; ++mi)
#pragma unroll
                for (int di = 0; di < 8; ++di)
                    acc[mi][di] = fmaf(vm[mi], kv[di], acc[mi][di]);
#pragma unroll
            for (int di = 0; di < 8; ++di) zz[di] += kv[di];
        }
    }

    __syncthreads();                           // all waves done streaming
    if (t < DDIM) qb[t] = elup1(query[(size_t)pair * DDIM + t]);

    // merge 16 wave-partials -> 4 buffers in parallel (4 barriered rounds)
    const int g = wave >> 2;                   // buffer group 0..3
    float* mb = &buf4[g][0];
    for (int rr = 0; rr < 4; ++rr) {
        if ((wave & 3) == rr) {
#pragma unroll
            for (int mi = 0; mi < 8; ++mi) {
                float4* row = (float4*)&mb[(m0 + mi) * DDIM + d0];
                if (rr == 0) {
                    row[0] = make_float4(acc[mi][0], acc[mi][1], acc[mi][2], acc[mi][3]);
                    row[1] = make_float4(acc[mi][4], acc[mi][5], acc[mi][6], acc[mi][7]);
                } else {
                    float4 a = row[0], b = row[1];
                    a.x += acc[mi][0]; a.y += acc[mi][1]; a.z += acc[mi][2]; a.w += acc[mi][3];
                    b.x += acc[mi][4]; b.y += acc[mi][5]; b.z += acc[mi][6]; b.w += acc[mi][7];
                    row[0] = a; row[1] = b;
                }
            }
            if (m0 == 0) {
#pragma unroll
                for (int i = 0; i < 8; ++i) {
                    if (rr == 0) zb4[g][d0 + i] = zz[i];
                    else         zb4[g][d0 + i] += zz[i];
                }
            }
        }
        __syncthreads();
    }

    // final 4-way sum; write S_state; keep summed copy in buf4[0] for V_out
    {
        const int e = t * 4;                   // 1024 threads x 4 = 4096
        float4 a = *(const float4*)&buf4[0][e];
        const float4 b  = *(const float4*)&buf4[1][e];
        const float4 c2 = *(const float4*)&buf4[2][e];
        const float4 d  = *(const float4*)&buf4[3][e];
        a.x += b.x + c2.x + d.x;
        a.y += b.y + c2.y + d.y;
        a.z += b.z + c2.z + d.z;
        a.w += b.w + c2.w + d.w;
        *(float4*)&out[OUT_SOFF + (size_t)pair * (MDIM * DDIM) + e] = a;
        *(float4*)&buf4[0][e] = a;
    }
    if (t < DDIM) {
        const float zv = zb4[0][t] + zb4[1][t] + zb4[2][t] + zb4[3][t];
        out[OUT_ZOFF + (size_t)pair * DDIM + t] = zv;
        zb4[0][t] = zv;
    }
    __syncthreads();

    // epilogue: wave 0, lane = m
    if (wave == 0) {
        float zp = qb[lane] * zb4[0][lane];
#pragma unroll
        for (int off = 32; off >= 1; off >>= 1) zp += __shfl_xor(zp, off, 64);
        const float qz = 1.0f / (zp + 1e-6f);
        float vs = 0.0f;
#pragma unroll
        for (int d = 0; d < DDIM; d += 4) {
            const float4 sv = *(const float4*)&buf4[0][lane * DDIM + d];
            vs = fmaf(qb[d],     sv.x, vs);
            vs = fmaf(qb[d + 1], sv.y, vs);
            vs = fmaf(qb[d + 2], sv.z, vs);
            vs = fmaf(qb[d + 3], sv.w, vs);
        }
        out[(size_t)pair * MDIM + lane] = qz * vs;
    }
}

extern "C" void kernel_launch(void* const* d_in, const int* in_sizes, int n_in,
                              void* d_out, int out_size, void* d_ws, size_t ws_size,
                              hipStream_t stream) {
    const float* q  = (const float*)d_in[0];
    const float* k  = (const float*)d_in[1];
    const float* v  = (const float*)d_in[2];
    const float* km = (const float*)d_in[3];
    float* out = (float*)d_out;
    rcla_fused<<<dim3(256), dim3(1024), 0, stream>>>(q, k, v, km, out);
}

// Round 5
// 170.576 us; speedup vs baseline: 5.6329x; 5.6329x over previous
//
#include <hip/hip_runtime.h>

// RecurrentCrossLinearAttention: N=16, S=4096, H=16, D=64, M=64, fp32.
// Round 5: wave-autonomous hot loop inside the PROVEN shell (512 thr,
// launch_bounds(512,2) -> 124 VGPR no-spill, grid 256 = 1 block/CU).
//  - V goes global->reg directly (no LDS): halves DS-pipe traffic (82->41us)
//  - zero __syncthreads in hot loop: per-wave private K slices, in-order DS
//  - rotating register prefetch (issue-after-consume), 1-chunk distance
//  - Z accumulated on the staging side (4 regs), shfl-reduced at the end
// DANGER ZONE (learned r2/r4): (512,4)/(1024,1) cap VGPR=64 -> acc spills.

#define S_LEN  4096
#define NHEAD  16
#define DDIM   64
#define MDIM   64
#define NWAVE  8                      // waves per 512-thread block
#define RPW    (S_LEN / NWAVE)        // 512 rows per wave
#define CROWS  4                      // rows per chunk
#define NCH    (RPW / CROWS)          // 128 chunks

#define OUT_SOFF  (16 * 16 * 64)
#define OUT_ZOFF  (OUT_SOFF + 16 * 16 * 64 * 64)

__device__ __forceinline__ float elup1(float x) {
    // elu(x) + 1 = x+1 (x>0) else exp(x)
    return x > 0.0f ? x + 1.0f : __expf(x);
}

__global__ __launch_bounds__(512, 2)
void rcla_fused(const float* __restrict__ query,
                const float* __restrict__ keys,
                const float* __restrict__ values,
                const float* __restrict__ kmask,
                float* __restrict__ out)
{
    __shared__ float Ks[NWAVE][CROWS][DDIM];   // 8 KB: per-wave K slices
    __shared__ float buf2[2][MDIM * DDIM];     // 32 KB merge buffers
    __shared__ float zb2[2][DDIM];
    __shared__ float qb[DDIM];

    const int t    = threadIdx.x;
    const int wave = t >> 6;
    const int lane = t & 63;
    const int pair = blockIdx.x;               // n*16 + h
    const int nIdx = pair >> 4;
    const int hIdx = pair & 15;

    const int srow = lane >> 4;                // 0..3 staging row in chunk
    const int scol = (lane & 15) * 4;          // staging cols (K)
    const int m0   = ((lane >> 3) & 7) * 8;    // acc tile row block (V side)
    const int d0   = (lane & 7) * 8;           // acc tile col block (K side)

    const size_t rowStride = (size_t)NHEAD * DDIM;   // 1024 floats
    const int sBase = wave * RPW;

    const float* kp = keys + ((size_t)nIdx * S_LEN + sBase + srow) * rowStride
                           + (size_t)hIdx * DDIM + scol;
    const float* mp = kmask + (size_t)nIdx * S_LEN + sBase + srow;
    const float* vbase = values + ((size_t)nIdx * S_LEN + sBase) * rowStride
                                + (size_t)hIdx * DDIM + m0;
    // two V pointers with +/-512-float (2048 B) imm offsets covering 4 rows
    const float* vpA = vbase + 512;                    // rows 0,1
    const float* vpB = vbase + 2 * rowStride + 512;    // rows 2,3

    float acc[8][8];
#pragma unroll
    for (int i = 0; i < 8; ++i)
#pragma unroll
        for (int j = 0; j < 8; ++j) acc[i][j] = 0.0f;
    float4 zst = make_float4(0.f, 0.f, 0.f, 0.f);      // staging-side Z partial

    // ---- prologue: chunk-0 loads ----
    float4 KC = *(const float4*)kp;
    float  MC = *mp;
    float4 VC[8];
#pragma unroll
    for (int r = 0; r < CROWS; ++r) {
        const float* pr = (r == 0) ? vpA - 512 : (r == 1) ? vpA + 512
                        : (r == 2) ? vpB - 512 : vpB + 512;
        VC[2*r]     = *(const float4*)pr;
        VC[2*r + 1] = *(const float4*)(pr + 4);
    }
    vpA += CROWS * rowStride;                  // point at chunk 1
    vpB += CROWS * rowStride;

    auto chunk_body = [&](bool pre) {
        // transform + stage this chunk's K (waits on in-flight KC/MC)
        float4 kt;
        kt.x = elup1(KC.x) * MC;  kt.y = elup1(KC.y) * MC;
        kt.z = elup1(KC.z) * MC;  kt.w = elup1(KC.w) * MC;
        zst.x += kt.x; zst.y += kt.y; zst.z += kt.z; zst.w += kt.w;
        *(float4*)&Ks[wave][srow][scol] = kt;
        if (pre) {                              // K/mask prefetch (next chunk)
            kp += CROWS * rowStride; mp += CROWS;
            KC = *(const float4*)kp;
            MC = *mp;
        }
#pragma unroll
        for (int r = 0; r < CROWS; ++r) {
            // per-wave in-order DS pipe: these reads see this chunk's writes
            const float4 kk0 = *(const float4*)&Ks[wave][r][d0];
            const float4 kk1 = *(const float4*)&Ks[wave][r][d0 + 4];
            const float4 va = VC[2*r];
            const float4 vb = VC[2*r + 1];
            if (pre) {                          // V prefetch, issue-after-copy
                const float* pr = (r == 0) ? vpA - 512 : (r == 1) ? vpA + 512
                                : (r == 2) ? vpB - 512 : vpB + 512;
                VC[2*r]     = *(const float4*)pr;
                VC[2*r + 1] = *(const float4*)(pr + 4);
            }
            const float vmv[8] = {va.x, va.y, va.z, va.w, vb.x, vb.y, vb.z, vb.w};
            const float kvv[8] = {kk0.x, kk0.y, kk0.z, kk0.w, kk1.x, kk1.y, kk1.z, kk1.w};
#pragma unroll
            for (int mi = 0; mi < 8; ++mi)
#pragma unroll
                for (int di = 0; di < 8; ++di)
                    acc[mi][di] = fmaf(vmv[mi], kvv[di], acc[mi][di]);
        }
        if (pre) { vpA += CROWS * rowStride; vpB += CROWS * rowStride; }
    };

    for (int c = 0; c < NCH - 1; ++c) chunk_body(true);
    chunk_body(false);

    // ---- reduce zst across the 4 srow groups (lanes ^16, ^32) ----
    zst.x += __shfl_xor(zst.x, 16, 64); zst.y += __shfl_xor(zst.y, 16, 64);
    zst.z += __shfl_xor(zst.z, 16, 64); zst.w += __shfl_xor(zst.w, 16, 64);
    zst.x += __shfl_xor(zst.x, 32, 64); zst.y += __shfl_xor(zst.y, 32, 64);
    zst.z += __shfl_xor(zst.z, 32, 64); zst.w += __shfl_xor(zst.w, 32, 64);

    __syncthreads();                            // all waves done streaming
    if (t < DDIM) qb[t] = elup1(query[(size_t)pair * DDIM + t]);

    // ---- merge 8 wave-partials -> 2 buffers, 4 barriered rounds ----
    const int g = wave >> 2;
    float* mb = &buf2[g][0];
    for (int rr = 0; rr < 4; ++rr) {
        if ((wave & 3) == rr) {
#pragma unroll
            for (int mi = 0; mi < 8; ++mi) {
                float4* row = (float4*)&mb[(m0 + mi) * DDIM + d0];
                if (rr == 0) {
                    row[0] = make_float4(acc[mi][0], acc[mi][1], acc[mi][2], acc[mi][3]);
                    row[1] = make_float4(acc[mi][4], acc[mi][5], acc[mi][6], acc[mi][7]);
                } else {
                    float4 a = row[0], b = row[1];
                    a.x += acc[mi][0]; a.y += acc[mi][1]; a.z += acc[mi][2]; a.w += acc[mi][3];
                    b.x += acc[mi][4]; b.y += acc[mi][5]; b.z += acc[mi][6]; b.w += acc[mi][7];
                    row[0] = a; row[1] = b;
                }
            }
            if (lane < 16) {                    // srow==0 lanes cover all cols
                if (rr == 0) {
                    zb2[g][scol]     = zst.x;  zb2[g][scol + 1] = zst.y;
                    zb2[g][scol + 2] = zst.z;  zb2[g][scol + 3] = zst.w;
                } else {
                    zb2[g][scol]     += zst.x; zb2[g][scol + 1] += zst.y;
                    zb2[g][scol + 2] += zst.z; zb2[g][scol + 3] += zst.w;
                }
            }
        }
        __syncthreads();
    }

    // ---- final 2-way sum; write S_state; keep copy for epilogue ----
    {
        const int e = t * 8;                    // 512 threads x 8 = 4096
        float4 a0 = *(const float4*)&buf2[0][e];
        float4 a1 = *(const float4*)&buf2[0][e + 4];
        const float4 b0 = *(const float4*)&buf2[1][e];
        const float4 b1 = *(const float4*)&buf2[1][e + 4];
        a0.x += b0.x; a0.y += b0.y; a0.z += b0.z; a0.w += b0.w;
        a1.x += b1.x; a1.y += b1.y; a1.z += b1.z; a1.w += b1.w;
        float* dst = out + OUT_SOFF + (size_t)pair * (MDIM * DDIM) + e;
        *(float4*)dst       = a0;
        *(float4*)(dst + 4) = a1;
        *(float4*)&buf2[0][e]     = a0;
        *(float4*)&buf2[0][e + 4] = a1;
    }
    if (t < DDIM) {
        const float zv = zb2[0][t] + zb2[1][t];
        out[OUT_ZOFF + (size_t)pair * DDIM + t] = zv;
        zb2[0][t] = zv;
    }
    __syncthreads();

    // ---- epilogue: wave 0, lane = m ----
    if (wave == 0) {
        float zp = qb[lane] * zb2[0][lane];
#pragma unroll
        for (int off = 32; off >= 1; off >>= 1) zp += __shfl_xor(zp, off, 64);
        const float qz = 1.0f / (zp + 1e-6f);
        float vs = 0.0f;
#pragma unroll
        for (int d = 0; d < DDIM; d += 4) {
            const float4 sv = *(const float4*)&buf2[0][lane * DDIM + d];
            vs = fmaf(qb[d],     sv.x, vs);
            vs = fmaf(qb[d + 1], sv.y, vs);
            vs = fmaf(qb[d + 2], sv.z, vs);
            vs = fmaf(qb[d + 3], sv.w, vs);
        }
        out[(size_t)pair * MDIM + lane] = qz * vs;
    }
}

extern "C" void kernel_launch(void* const* d_in, const int* in_sizes, int n_in,
                              void* d_out, int out_size, void* d_ws, size_t ws_size,
                              hipStream_t stream) {
    const float* q  = (const float*)d_in[0];
    const float* k  = (const float*)d_in[1];
    const float* v  = (const float*)d_in[2];
    const float* km = (const float*)d_in[3];
    float* out = (float*)d_out;
    rcla_fused<<<dim3(256), dim3(512), 0, stream>>>(q, k, v, km, out);
}